// Round 6
// baseline (314.742 us; speedup 1.0000x reference)
//
#include <hip/hip_runtime.h>
#include <hip/hip_bf16.h>
#include <cstdint>

// Block: B=2, T=2048, C=1024, H=16, D=64. Inputs/outputs fp32; internal bf16
// MFMA, fp32 accum. GEMM: XOR-swizzled LDS (conflict-free, measured 0),
// 128x128/BK=64 (QKV, ff1) and 64x64/BK=128 (proj, ff2 -> 1024 blocks, 4/CU).
// Attention: 64-wide chunks, max-free softmax, one q-tile per block (1024
// blocks, long-first dispatch), XCD-aware decode (bh%8 == id%8).

typedef unsigned short u16;
typedef __attribute__((ext_vector_type(8))) __bf16 bf16x8;
typedef __attribute__((ext_vector_type(4))) float f32x4;

__device__ __forceinline__ u16 f2b(float f) {
    return __builtin_bit_cast(unsigned short, __float2bfloat16(f));
}

__device__ __forceinline__ f32x4 mfma16(bf16x8 a, bf16x8 b, f32x4 c) {
    return __builtin_amdgcn_mfma_f32_16x16x32_bf16(a, b, c, 0, 0, 0);
}

// async global->LDS: each lane's 16B lands at lds_base + lane*16.
__device__ __forceinline__ void load_lds16(const u16* g, u16* l) {
    __builtin_amdgcn_global_load_lds(
        (const __attribute__((address_space(1))) unsigned int*)g,
        (__attribute__((address_space(3))) unsigned int*)l, 16, 0, 0);
}

// ------------- all weight transposes in ONE launch --------------------------
__global__ __launch_bounds__(256) void transpose_all(
    const float* __restrict__ wq, const float* __restrict__ wk,
    const float* __restrict__ wv, const float* __restrict__ wp,
    const float* __restrict__ w1, const float* __restrict__ w2,
    u16* __restrict__ wqkvt, u16* __restrict__ wpt,
    u16* __restrict__ w1t, u16* __restrict__ w2t)
{
    __shared__ float tile[32][33];
    int id = blockIdx.x;
    const float* src; u16* dst; int R, C, bx, by;
    if (id < 3072) {                       // wq|wk|wv: 16 batches of 1024x64
        const int m = id >> 10;
        src = (m == 0) ? wq : (m == 1) ? wk : wv;
        dst = wqkvt + m * 1048576u;
        int t = id & 1023;
        const int b = t >> 6; t &= 63;
        R = 1024; C = 64; bx = t & 1; by = t >> 1;
        src += (size_t)b * 65536; dst += (size_t)b * 65536;
    } else if (id < 4096) {                // wp 1024x1024
        int t = id - 3072; src = wp; dst = wpt;
        R = 1024; C = 1024; bx = t & 31; by = t >> 5;
    } else if (id < 8192) {                // w1 1024x4096
        int t = id - 4096; src = w1; dst = w1t;
        R = 1024; C = 4096; bx = t & 127; by = t >> 7;
    } else {                               // w2 4096x1024
        int t = id - 8192; src = w2; dst = w2t;
        R = 4096; C = 1024; bx = t & 31; by = t >> 5;
    }
    const int tx = threadIdx.x, ty = threadIdx.y;
    const int c0 = bx * 32, r0 = by * 32;
#pragma unroll
    for (int i = 0; i < 4; ++i) {
        int r = ty * 4 + i;
        tile[r][tx] = src[(size_t)(r0 + r) * C + c0 + tx];
    }
    __syncthreads();
#pragma unroll
    for (int i = 0; i < 4; ++i) {
        int r = ty * 4 + i;
        dst[(size_t)(c0 + r) * R + r0 + tx] = f2b(tile[tx][r]);
    }
}

// ------------- layernorm: fp32 row of 1024 -> bf16 --------------------------
__global__ __launch_bounds__(256) void ln_kernel(
    const float* __restrict__ x, const float* __restrict__ g,
    const float* __restrict__ be, u16* __restrict__ out)
{
    const int row = blockIdx.x;
    const int tid = threadIdx.x;
    const float* xr = x + (size_t)row * 1024;
    float v[4];
#pragma unroll
    for (int i = 0; i < 4; ++i) v[i] = xr[tid + i * 256];
    float s = v[0] + v[1] + v[2] + v[3];
    float q = v[0]*v[0] + v[1]*v[1] + v[2]*v[2] + v[3]*v[3];
#pragma unroll
    for (int o = 1; o < 64; o <<= 1) {
        s += __shfl_xor(s, o, 64);
        q += __shfl_xor(q, o, 64);
    }
    __shared__ float red[8];
    const int wave = tid >> 6;
    if ((tid & 63) == 0) { red[wave] = s; red[4 + wave] = q; }
    __syncthreads();
    s = red[0] + red[1] + red[2] + red[3];
    q = red[4] + red[5] + red[6] + red[7];
    const float mu = s * (1.0f / 1024.0f);
    const float var = q * (1.0f / 1024.0f) - mu * mu;
    const float rstd = rsqrtf(var + 1e-5f);
#pragma unroll
    for (int i = 0; i < 4; ++i) {
        int idx = tid + i * 256;
        out[(size_t)row * 1024 + idx] = f2b((v[i] - mu) * rstd * g[idx] + be[idx]);
    }
}

// ------------- GEMM: C[M][N] = A[M][K] (bf16 rowmajor) * Bt[N][K] -----------
// BK/64 sub-stages; each sub-stage: rows of 64 k (8 x 16B slots); slot q of
// row r holds k-block q ^ (r&7)  -> conflict-free frag reads (measured 0).
// EPI: 0=fused QKV (N=3072); 3=proj out_f=resid+acc+bias;
//      4=ff1 relu(acc+bias) bf16; 5=ff2 out_f=resid+acc+bias.
template <int EPI, int TM, int TN, int WM, int WN, int BK>
__global__ __launch_bounds__(256, 2) void gemm_bt(
    const u16* __restrict__ A, const u16* __restrict__ Bt,
    int M, int N, int K,
    const float* __restrict__ bias, const float* __restrict__ resid_f,
    u16* __restrict__ out_b, float* __restrict__ out_f)
{
    constexpr int MI = WM / 16, NI = WN / 16;
    constexpr int MWAVES = TM / WM;
    constexpr int SS = BK / 64;
    __shared__ alignas(16) u16 As[TM * BK];
    __shared__ alignas(16) u16 Bs[TN * BK];
    const int tid = threadIdx.x;
    const int wave = tid >> 6, lane = tid & 63;
    const int lr = lane >> 4, lc = lane & 15;
    const int m0 = blockIdx.x * TM, n0 = blockIdx.y * TN;
    const int wm = (wave % MWAVES) * WM, wn = (wave / MWAVES) * WN;

    f32x4 acc[MI][NI];
#pragma unroll
    for (int i = 0; i < MI; ++i)
#pragma unroll
        for (int j = 0; j < NI; ++j) acc[i][j] = (f32x4){0.f, 0.f, 0.f, 0.f};

    // staging: per 4KB line (32 rows x 64 k), wave covers 8 rows; lane: row
    // lane>>3, slot lane&7, holding k-block (lane&7)^(row&7).
    const int srow = lane >> 3;
    const int skb = (lane & 7) ^ srow;
    const u16* Agp = A + (size_t)(m0 + wave * 8 + srow) * K + skb * 8;
    const u16* Bgp = Bt + (size_t)(n0 + wave * 8 + srow) * K + skb * 8;
    const int ldst = wave * 512;

    for (int k0 = 0; k0 < K; k0 += BK) {
#pragma unroll
        for (int s = 0; s < SS; ++s) {
#pragma unroll
            for (int i = 0; i < TM / 32; ++i)
                load_lds16(Agp + (size_t)i * 32 * K + k0 + s * 64,
                           As + s * TM * 64 + i * 2048 + ldst);
#pragma unroll
            for (int i = 0; i < TN / 32; ++i)
                load_lds16(Bgp + (size_t)i * 32 * K + k0 + s * 64,
                           Bs + s * TN * 64 + i * 2048 + ldst);
        }
        __syncthreads();
#pragma unroll
        for (int h = 0; h < BK / 32; ++h) {
            const int ss = h >> 1, hh = h & 1;
            const int qh = ((hh * 4 + lr) ^ (lc & 7)) * 8;
            bf16x8 af[MI], bfr[NI];
#pragma unroll
            for (int i = 0; i < MI; ++i)
                af[i] = *(const bf16x8*)&As[ss * TM * 64 + (wm + i * 16 + lc) * 64 + qh];
#pragma unroll
            for (int j = 0; j < NI; ++j)
                bfr[j] = *(const bf16x8*)&Bs[ss * TN * 64 + (wn + j * 16 + lc) * 64 + qh];
#pragma unroll
            for (int i = 0; i < MI; ++i)
#pragma unroll
                for (int j = 0; j < NI; ++j)
                    acc[i][j] = mfma16(af[i], bfr[j], acc[i][j]);
        }
        __syncthreads();
    }

#pragma unroll
    for (int i = 0; i < MI; ++i) {
#pragma unroll
        for (int j = 0; j < NI; ++j) {
#pragma unroll
            for (int r = 0; r < 4; ++r) {
                const int m = m0 + wm + i * 16 + lr * 4 + r;
                const int n = n0 + wn + j * 16 + lc;
                const float v = acc[i][j][r];
                if (EPI == 0) {
                    const int group = n >> 10, nn = n & 1023;
                    const int hh = nn >> 6, dd = nn & 63;
                    const int bb = m >> 11, tt = m & 2047;
                    if (group == 0)
                        out_b[(((size_t)(bb * 16 + hh) * 2048) + tt) * 64 + dd] =
                            f2b(v * 0.125f);
                    else if (group == 1)
                        out_b[4194304u + (((size_t)(bb * 16 + hh) * 2048) + tt) * 64 + dd] =
                            f2b(v);
                    else
                        out_b[8388608u + (((size_t)(bb * 16 + hh) * 64) + dd) * 2048 + tt] =
                            f2b(v);
                } else if (EPI == 4) {
                    size_t idx = (size_t)m * N + n;
                    float rv = v + bias[n];
                    out_b[idx] = f2b(rv > 0.f ? rv : 0.f);
                } else {   // 3, 5
                    size_t idx = (size_t)m * N + n;
                    out_f[idx] = resid_f[idx] + v + bias[n];
                }
            }
        }
    }
}

// ------------- flash attention: causal, D=64, max-free softmax --------------
// 1D grid 1024: one q-tile (64 rows) per block. Decode: xcd=id&7,
// qt=31-((id>>3)&31) (long blocks dispatch first), bh=(id>>8)*8+xcd so all
// 32 q-blocks of a bh run on one XCD (K/V 4 bh x 512 KB = 2 MB < L2/XCD).
// LDS XOR-swizzled: slot q of row r holds block (q ^ (r&7)).
__global__ __launch_bounds__(256) void attn_kernel(
    const u16* __restrict__ qb, const u16* __restrict__ kb,
    const u16* __restrict__ vtb, u16* __restrict__ ob)
{
    const int id = blockIdx.x;
    const int xcd = id & 7;
    const int qt = 31 - ((id >> 3) & 31);
    const int bh = (id >> 8) * 8 + xcd;
    const int b = bh >> 4, h = bh & 15;
    const int tid = threadIdx.x, wave = tid >> 6, lane = tid & 63;
    const int lr = lane >> 4, lc = lane & 15;
    const int qx = lc & 7;
    __shared__ alignas(16) u16 Ks[64 * 64];    // [s][d-blocks swizzled]
    __shared__ alignas(16) u16 Vts[64 * 64];   // [d][s-blocks swizzled]
    __shared__ alignas(16) u16 Ps[4][16 * 64]; // per-wave [t][s-blocks swizzled]
    const size_t base = (size_t)bh * (2048 * 64);

    const int srow = lane >> 3;                // 0..7 within 1KB stage
    const int sdb = (lane & 7) ^ srow;         // swizzled source block
    const u16* kg0 = kb + base + (size_t)(wave * 16 + srow) * 64 + sdb * 8;
    const u16* vg0 = vtb + base + (size_t)(wave * 16 + srow) * 2048 + sdb * 8;
    u16* KsW = Ks + wave * 16 * 64;
    u16* VsW = Vts + wave * 16 * 64;
    const int q0 = (lr ^ qx) * 8;              // k-block lr
    const int q1 = ((4 + lr) ^ qx) * 8;        // k-block 4+lr

    const int t0 = qt * 64;
    const int trow = t0 + wave * 16 + lc;
    const bf16x8 qf0 = *(const bf16x8*)&qb[base + (size_t)trow * 64 + lr * 8];
    const bf16x8 qf1 = *(const bf16x8*)&qb[base + (size_t)trow * 64 + 32 + lr * 8];
    f32x4 O[4];
    float pls[4];
#pragma unroll
    for (int j = 0; j < 4; ++j) O[j] = (f32x4){0.f, 0.f, 0.f, 0.f};
#pragma unroll
    for (int r = 0; r < 4; ++r) pls[r] = 0.f;

    for (int c = 0; c <= qt; ++c) {
        const int s0 = c * 64;
        load_lds16(kg0 + (size_t)s0 * 64, KsW);
        load_lds16(kg0 + (size_t)s0 * 64 + 512, KsW + 512);
        load_lds16(vg0 + s0, VsW);
        load_lds16(vg0 + s0 + 8 * 2048, VsW + 512);
        __syncthreads();

        f32x4 sc[4];
#pragma unroll
        for (int j = 0; j < 4; ++j) sc[j] = (f32x4){0.f, 0.f, 0.f, 0.f};
#pragma unroll
        for (int j = 0; j < 4; ++j) {
            const int row = (j * 16 + lc) * 64;
            bf16x8 k0 = *(const bf16x8*)&Ks[row + q0];
            bf16x8 k1 = *(const bf16x8*)&Ks[row + q1];
            sc[j] = mfma16(qf0, k0, sc[j]);
            sc[j] = mfma16(qf1, k1, sc[j]);
        }
        const bool diag = (c == qt);
#pragma unroll
        for (int r = 0; r < 4; ++r) {
            const int tl = lr * 4 + r;
#pragma unroll
            for (int j = 0; j < 4; ++j) {
                float pv = __expf(sc[j][r]);
                if (diag && (j * 16 + lc > wave * 16 + tl)) pv = 0.f;
                pls[r] += pv;
                const int sb = j * 2 + (lc >> 3);
                Ps[wave][tl * 64 + ((sb ^ (tl & 7)) * 8) + (lc & 7)] = f2b(pv);
            }
        }
        const bf16x8 pf0 = *(const bf16x8*)&Ps[wave][lc * 64 + q0];
        const bf16x8 pf1 = *(const bf16x8*)&Ps[wave][lc * 64 + q1];
#pragma unroll
        for (int j = 0; j < 4; ++j) {
            const int row = (j * 16 + lc) * 64;
            bf16x8 v0 = *(const bf16x8*)&Vts[row + q0];
            bf16x8 v1 = *(const bf16x8*)&Vts[row + q1];
            O[j] = mfma16(pf0, v0, O[j]);
            O[j] = mfma16(pf1, v1, O[j]);
        }
        __syncthreads();
    }

    float linv[4];
#pragma unroll
    for (int r = 0; r < 4; ++r) {
        float l = pls[r];
        l += __shfl_xor(l, 1, 64);
        l += __shfl_xor(l, 2, 64);
        l += __shfl_xor(l, 4, 64);
        l += __shfl_xor(l, 8, 64);
        linv[r] = 1.0f / l;
    }
#pragma unroll
    for (int j = 0; j < 4; ++j)
#pragma unroll
        for (int r = 0; r < 4; ++r) {
            const int tr = t0 + wave * 16 + lr * 4 + r;
            ob[((size_t)b * 2048 + tr) * 1024 + h * 64 + j * 16 + lc] =
                f2b(O[j][r] * linv[r]);
        }
}

// ------------- launch -------------------------------------------------------
extern "C" void kernel_launch(void* const* d_in, const int* in_sizes, int n_in,
                              void* d_out, int out_size, void* d_ws, size_t ws_size,
                              hipStream_t stream)
{
    (void)in_sizes; (void)n_in; (void)out_size; (void)ws_size;
    const float* x   = (const float*)d_in[0];
    const float* wq  = (const float*)d_in[1];
    const float* wk  = (const float*)d_in[2];
    const float* wv  = (const float*)d_in[3];
    const float* wp  = (const float*)d_in[4];
    const float* bp  = (const float*)d_in[5];
    const float* w1  = (const float*)d_in[6];
    const float* b1  = (const float*)d_in[7];
    const float* w2  = (const float*)d_in[8];
    const float* b2  = (const float*)d_in[9];
    const float* g1  = (const float*)d_in[10];
    const float* be1 = (const float*)d_in[11];
    const float* g2  = (const float*)d_in[12];
    const float* be2 = (const float*)d_in[13];
    float* out = (float*)d_out;

    char* ws = (char*)d_ws;
    const size_t MB = 1024ull * 1024;
    u16*   h1    = (u16*)(ws + 0);            // 8 MB (reused as h2)
    u16*   wqkvt = (u16*)(ws + 8 * MB);       // 6 MB (q|k|v transposed)
    u16*   wpt   = (u16*)(ws + 14 * MB);      // 2
    u16*   w1t   = (u16*)(ws + 16 * MB);      // 8
    u16*   w2t   = (u16*)(ws + 24 * MB);      // 8
    u16*   qkv   = (u16*)(ws + 32 * MB);      // 24 (q@0, k@+4M elems, v@+8M)
    u16*   attnb = (u16*)(ws + 56 * MB);      // 8
    u16*   ff1   = (u16*)(ws + 32 * MB);      // 32 (overlays qkv+attn, dead then)
    float* x2    = (float*)(ws + 64 * MB);    // 16
    u16*   h2    = h1;
    u16*   qb    = qkv;
    u16*   kbf   = qkv + 4194304u;
    u16*   vtb   = qkv + 8388608u;

    transpose_all<<<12288, dim3(32, 8), 0, stream>>>(
        wq, wk, wv, wp, w1, w2, wqkvt, wpt, w1t, w2t);

    ln_kernel<<<4096, 256, 0, stream>>>(x, g1, be1, h1);

    gemm_bt<0, 128, 128, 64, 64, 64><<<dim3(32, 24), 256, 0, stream>>>(
        h1, wqkvt, 4096, 3072, 1024, nullptr, nullptr, qkv, nullptr);

    attn_kernel<<<1024, 256, 0, stream>>>(qb, kbf, vtb, attnb);

    gemm_bt<3, 64, 64, 32, 32, 128><<<dim3(64, 16), 256, 0, stream>>>(
        attnb, wpt, 4096, 1024, 1024, bp, x, nullptr, x2);

    ln_kernel<<<4096, 256, 0, stream>>>(x2, g2, be2, h2);

    gemm_bt<4, 128, 128, 64, 64, 64><<<dim3(32, 32), 256, 0, stream>>>(
        h2, w1t, 4096, 4096, 1024, b1, nullptr, ff1, nullptr);

    gemm_bt<5, 64, 64, 32, 32, 128><<<dim3(64, 16), 256, 0, stream>>>(
        ff1, w2t, 4096, 1024, 4096, b2, x2, nullptr, out);
}